// Round 1
// baseline (209.075 us; speedup 1.0000x reference)
//
#include <hip/hip_runtime.h>
#include <hip/hip_bf16.h>

#define NB 16384
#define NC 1000
#define NCP 1008
#define ND 1024
#define NTILES 63   // 1008 / 16

typedef __attribute__((ext_vector_type(8))) short bf16x8;
typedef __attribute__((ext_vector_type(4))) float f32x4;

typedef __attribute__((address_space(1))) const void GV;
typedef __attribute__((address_space(3))) void LV;

__device__ __forceinline__ unsigned short f2bf(float f) {
  union { float f; unsigned u; } c; c.f = f;
  unsigned b = c.u;
  return (unsigned short)((b + 0x7fffu + ((b >> 16) & 1u)) >> 16);  // RNE, NaN-unsafe (inputs finite)
}

// ---------- prep: target f32 -> bf16 (padded to 1008 rows), exact f32 t2 ----------
__global__ __launch_bounds__(256) void prep_kernel(const float* __restrict__ Tf,
                                                   unsigned short* __restrict__ Tb,
                                                   float* __restrict__ t2) {
  const int c = blockIdx.x;      // 0..1007
  const int tid = threadIdx.x;   // 256 threads, 4 elems each
  if (c >= NC) {
    ushort4 z; z.x = z.y = z.z = z.w = 0;
    ((ushort4*)(Tb + (size_t)c * ND))[tid] = z;
    if (tid == 0) t2[c] = 1e30f;   // padding never wins argmin
    return;
  }
  float4 v = ((const float4*)(Tf + (size_t)c * ND))[tid];
  float ss = v.x * v.x + v.y * v.y + v.z * v.z + v.w * v.w;
  ushort4 o;
  o.x = f2bf(v.x); o.y = f2bf(v.y); o.z = f2bf(v.z); o.w = f2bf(v.w);
  ((ushort4*)(Tb + (size_t)c * ND))[tid] = o;
  #pragma unroll
  for (int m = 1; m < 64; m <<= 1) ss += __shfl_xor(ss, m, 64);
  __shared__ float red[4];
  if ((tid & 63) == 0) red[tid >> 6] = ss;
  __syncthreads();
  if (tid == 0) t2[c] = red[0] + red[1] + red[2] + red[3];
}

// ---------- stage one 16-col T tile (16 rows x 1024 bf16 = 32KB) into LDS ----------
// LDS layout is linear (global_load_lds requirement); the *source* address is
// XOR-swizzled so that reads can use byte ^= (row&7)<<4 (both-sides swizzle).
__device__ __forceinline__ void stage_tile(const unsigned short* __restrict__ Tb,
                                           int c0, char* dst, int tid) {
  const int w = tid >> 6, lane = tid & 63;
  #pragma unroll
  for (int i = 0; i < 8; ++i) {
    int o = i * 4096 + w * 1024 + lane * 16;          // linear LDS byte offset in tile
    int row = o >> 11;                                // 2048B per row
    int col = (o & 2047) ^ ((row & 7) << 4);          // inverse-swizzled source column
    const char* src = (const char*)Tb + (size_t)(c0 + row) * 2048 + col;
    __builtin_amdgcn_global_load_lds((GV*)src, (LV*)(dst + i * 4096 + w * 1024), 16, 0, 0);
  }
}

// ---------- mining + fused exact-distance epilogue ----------
// block = 4 waves, 64 rows; wave owns 16 rows with full-K bf16 A-frags in regs.
__global__ __launch_bounds__(256, 1) void mine_kernel(
    const float* __restrict__ X, const int* __restrict__ labels,
    const float* __restrict__ Tf, const unsigned short* __restrict__ Tb,
    const float* __restrict__ t2g, float* __restrict__ out) {
  __shared__ char sT[2][32768];   // double-buffered 16x1024 bf16 tile
  const int tid = threadIdx.x;
  const int w = tid >> 6, lane = tid & 63;
  const int l15 = lane & 15, l4 = lane >> 4;
  const int rowbase = blockIdx.x * 64 + w * 16;

  stage_tile(Tb, 0, sT[0], tid);

  // A fragments: lane holds X[rowbase+l15][kk*32 + l4*8 + j], j=0..7 (k-consistent with B reads)
  bf16x8 afrag[32];
  const float* xrow = X + (size_t)(rowbase + l15) * ND;
  #pragma unroll
  for (int kk = 0; kk < 32; ++kk) {
    float4 v0 = *(const float4*)(xrow + kk * 32 + l4 * 8);
    float4 v1 = *(const float4*)(xrow + kk * 32 + l4 * 8 + 4);
    bf16x8 f;
    f[0] = (short)f2bf(v0.x); f[1] = (short)f2bf(v0.y);
    f[2] = (short)f2bf(v0.z); f[3] = (short)f2bf(v0.w);
    f[4] = (short)f2bf(v1.x); f[5] = (short)f2bf(v1.y);
    f[6] = (short)f2bf(v1.z); f[7] = (short)f2bf(v1.w);
    afrag[kk] = f;
  }

  // labels for the 4 rows this lane's accumulator registers cover (D row = l4*4 + r)
  int lab[4];
  #pragma unroll
  for (int r = 0; r < 4; ++r) lab[r] = labels[rowbase + l4 * 4 + r];

  // ds_read bases with the (row&7)<<4 XOR swizzle folded into two bases
  // addr(kk) = l15*2048 + ((kk*64 + l4*16) ^ ((l15&7)<<4)); even kk uses baseE, odd baseO
  const int s = (l15 & 7) << 4;
  const int lo = (l4 * 16) ^ (s & 0x30);
  const int baseE = l15 * 2048 + lo + (s & 0x40);
  const int baseO = l15 * 2048 + lo - (s & 0x40);

  float minv[4] = {3.0e38f, 3.0e38f, 3.0e38f, 3.0e38f};
  int mini[4] = {0, 0, 0, 0};

  int cur = 0;
  for (int t = 0; t < NTILES; ++t) {
    __syncthreads();                                   // buf[cur] staged (vmcnt drained)
    if (t + 1 < NTILES) stage_tile(Tb, (t + 1) * 16, sT[cur ^ 1], tid);
    const char* bufp = sT[cur];
    f32x4 acc[4] = {{0,0,0,0},{0,0,0,0},{0,0,0,0},{0,0,0,0}};  // 4 chains for MFMA ILP
    #pragma unroll
    for (int kk = 0; kk < 32; ++kk) {
      bf16x8 b = *(const bf16x8*)(bufp + ((kk & 1) ? baseO : baseE) + kk * 64);
      acc[kk & 3] = __builtin_amdgcn_mfma_f32_16x16x32_bf16(afrag[kk], b, acc[kk & 3], 0, 0, 0);
    }
    f32x4 ssum = (acc[0] + acc[1]) + (acc[2] + acc[3]);
    const int c = t * 16 + l15;                        // this lane's candidate column
    const float t2v = t2g[c];
    #pragma unroll
    for (int r = 0; r < 4; ++r) {
      float sc = t2v - 2.0f * ssum[r];                 // argmin of (t2 - 2 x.t) == argmin d2
      sc = (c == lab[r]) ? 3.2e38f : sc;               // exclude own class
      if (sc < minv[r]) { minv[r] = sc; mini[r] = c; } // strict < keeps first index on ties
    }
    cur ^= 1;
  }

  // reduce argmin across the 16 lanes (cols) of each row group
  #pragma unroll
  for (int m = 1; m < 16; m <<= 1) {
    #pragma unroll
    for (int r = 0; r < 4; ++r) {
      float v2 = __shfl_xor(minv[r], m, 64);
      int i2 = __shfl_xor(mini[r], m, 64);
      if (v2 < minv[r] || (v2 == minv[r] && i2 < mini[r])) { minv[r] = v2; mini[r] = i2; }
    }
  }

  // fused epilogue: exact f32 distances for (anchor, pos, mined neg), hinge, mean
  float wacc = 0.0f;
  #pragma unroll
  for (int r = 0; r < 16; ++r) {                       // full unroll: mini[r&3] stays static
    const int negc = __shfl(mini[r & 3], (r >> 2) << 4, 64);
    const int posc = labels[rowbase + r];
    const float* xr = X + (size_t)(rowbase + r) * ND;
    const float* pr = Tf + (size_t)posc * ND;
    const float* nr = Tf + (size_t)negc * ND;
    float sap = 0.0f, san = 0.0f;
    #pragma unroll
    for (int q = 0; q < 4; ++q) {
      float4 xv = ((const float4*)xr)[lane + q * 64];
      float4 pv = ((const float4*)pr)[lane + q * 64];
      float4 nv = ((const float4*)nr)[lane + q * 64];
      float d;
      d = xv.x - pv.x + 1e-6f; sap += d * d;
      d = xv.y - pv.y + 1e-6f; sap += d * d;
      d = xv.z - pv.z + 1e-6f; sap += d * d;
      d = xv.w - pv.w + 1e-6f; sap += d * d;
      d = xv.x - nv.x + 1e-6f; san += d * d;
      d = xv.y - nv.y + 1e-6f; san += d * d;
      d = xv.z - nv.z + 1e-6f; san += d * d;
      d = xv.w - nv.w + 1e-6f; san += d * d;
    }
    #pragma unroll
    for (int m = 1; m < 64; m <<= 1) {
      sap += __shfl_xor(sap, m, 64);
      san += __shfl_xor(san, m, 64);
    }
    if (lane == 0) {
      float h = sqrtf(sap) - sqrtf(san) + 1.0f;        // d_ap - d_an + margin
      wacc += fmaxf(h, 0.0f);
    }
  }
  if (lane == 0) atomicAdd(out, wacc * (1.0f / (float)NB));
}

extern "C" void kernel_launch(void* const* d_in, const int* in_sizes, int n_in,
                              void* d_out, int out_size, void* d_ws, size_t ws_size,
                              hipStream_t stream) {
  const float* X = (const float*)d_in[0];        // [16384,1024] f32
  const int* labels = (const int*)d_in[1];       // [16384] int
  const float* Tf = (const float*)d_in[2];       // [1000,1024] f32
  float* out = (float*)d_out;                    // scalar f32

  unsigned short* Tb = (unsigned short*)d_ws;                       // 1008*1024 bf16 = 2,064,384 B
  float* t2 = (float*)((char*)d_ws + (size_t)NCP * ND * 2);         // 1008 f32

  hipMemsetAsync(d_out, 0, sizeof(float), stream);
  prep_kernel<<<NCP, 256, 0, stream>>>(Tf, Tb, t2);
  mine_kernel<<<NB / 64, 256, 0, stream>>>(X, labels, Tf, Tb, t2, out);
}

// Round 2
// 153.911 us; speedup vs baseline: 1.3584x; 1.3584x over previous
//
#include <hip/hip_runtime.h>
#include <hip/hip_bf16.h>

#define NB 16384
#define NC 1000
#define NCP 1024          // padded target count (pads score = +inf)
#define ND 1024
#define BM 128
#define BN 256
#define KSTEPS 32         // 1024 / 32
#define NCB 4             // column blocks = NCP / BN

typedef __attribute__((ext_vector_type(8))) short bf16x8;
typedef __attribute__((ext_vector_type(4))) float f32x4;

typedef __attribute__((address_space(1))) const void GV;
typedef __attribute__((address_space(3))) void LV;

__device__ __forceinline__ unsigned short f2bf(float f) {
  union { float f; unsigned u; } c; c.f = f;
  unsigned b = c.u;
  return (unsigned short)((b + 0x7fffu + ((b >> 16) & 1u)) >> 16);  // RNE
}
__device__ __forceinline__ unsigned pk2(float lo, float hi) {
  return ((unsigned)f2bf(hi) << 16) | (unsigned)f2bf(lo);
}

// ---------- prep: target f32 -> bf16 (padded to 1024 rows), exact f32 t2 ----------
__global__ __launch_bounds__(256) void prep_kernel(const float* __restrict__ Tf,
                                                   unsigned short* __restrict__ Tb,
                                                   float* __restrict__ t2) {
  const int c = blockIdx.x;      // 0..1023
  const int tid = threadIdx.x;   // 256 threads, 4 elems each
  if (c >= NC) {
    ushort4 z; z.x = z.y = z.z = z.w = 0;
    ((ushort4*)(Tb + (size_t)c * ND))[tid] = z;
    if (tid == 0) t2[c] = 1e30f;   // padding never wins argmin
    return;
  }
  float4 v = ((const float4*)(Tf + (size_t)c * ND))[tid];
  float ss = v.x * v.x + v.y * v.y + v.z * v.z + v.w * v.w;
  ushort4 o;
  o.x = f2bf(v.x); o.y = f2bf(v.y); o.z = f2bf(v.z); o.w = f2bf(v.w);
  ((ushort4*)(Tb + (size_t)c * ND))[tid] = o;
  #pragma unroll
  for (int m = 1; m < 64; m <<= 1) ss += __shfl_xor(ss, m, 64);
  __shared__ float red[4];
  if ((tid & 63) == 0) red[tid >> 6] = ss;
  __syncthreads();
  if (tid == 0) t2[c] = red[0] + red[1] + red[2] + red[3];
}

// ---------- fused GEMM + mining: scores s = t2[c] - 2 x.t, per-block row-min + lab score ----------
// 128x256 tile, BK=32, 8 waves (2x4), wave = 64x64 via 4x4 mfma_16x16x32_bf16.
__global__ __launch_bounds__(512, 4) void mine2_kernel(
    const float* __restrict__ X, const int* __restrict__ labels,
    const unsigned short* __restrict__ Tb, const float* __restrict__ t2g,
    float* __restrict__ x2g, float* __restrict__ slab, float2* __restrict__ pairs) {
  __shared__ char sA[2][BM * 64];     // [row][64B of k] bf16, 8KB each
  __shared__ char sB[2][BN * 64];     // [col][64B of k] bf16, 16KB each
  __shared__ int sLab[BM];
  __shared__ float2 sMin[BM][4];      // per-row per-wc partial (minval, idx)

  const int tid = threadIdx.x;
  const int lane = tid & 63;
  const int wid = tid >> 6;
  const int l15 = lane & 15, l4 = lane >> 4;
  const int wr = wid >> 2, wc = wid & 3;
  const int rb = (int)blockIdx.x >> 2, cb = (int)blockIdx.x & 3;
  const int rowbase = rb * BM, colbase = cb * BN;

  if (tid < BM) sLab[tid] = labels[rowbase + tid];

  // A staging coords: thread t -> row t/4, k-bytes (t&3)*16 .. +16 (8 f32 in, 8 bf16 out)
  const int arow = tid >> 2;
  const float* aptr = X + (size_t)(rowbase + arow) * ND + ((tid & 3) << 3);
  float ss = 0.0f;   // exact x2 partial (cb==0 blocks only)

  f32x4 acc[4][4] = {};
  int cur = 0;

  // ---- staging (A: global f32 -> regs -> cvt -> ds_write; B: global_load_lds x16B) ----
  auto stage = [&](int buf, int ks) {
    #pragma unroll
    for (int i = 0; i < 2; ++i) {
      const int o = i * 8192 + tid * 16;                 // 16KB B tile
      const char* src = (const char*)Tb + (size_t)(colbase + (o >> 6)) * 2048 + ks * 64 + (o & 63);
      __builtin_amdgcn_global_load_lds((GV*)src, (LV*)(sB[buf] + o), 16, 0, 0);
    }
    float4 v0 = *(const float4*)(aptr + ks * 32);
    float4 v1 = *(const float4*)(aptr + ks * 32 + 4);
    if (cb == 0) {
      ss += v0.x * v0.x + v0.y * v0.y + v0.z * v0.z + v0.w * v0.w
          + v1.x * v1.x + v1.y * v1.y + v1.z * v1.z + v1.w * v1.w;
    }
    uint4 w;
    w.x = pk2(v0.x, v0.y); w.y = pk2(v0.z, v0.w);
    w.z = pk2(v1.x, v1.y); w.w = pk2(v1.z, v1.w);
    *(uint4*)(sA[buf] + tid * 16) = w;                   // row = t/4, kb = (t&3)*16 (linear)
  };

  stage(0, 0);
  for (int ks = 0; ks < KSTEPS; ++ks) {
    __syncthreads();                                     // buf[cur] ready (vmcnt+lgkm drained)
    if (ks + 1 < KSTEPS) stage(cur ^ 1, ks + 1);
    const char* pa = sA[cur];
    const char* pb = sB[cur];
    bf16x8 af[4];
    #pragma unroll
    for (int m = 0; m < 4; ++m)
      af[m] = *(const bf16x8*)(pa + ((wr * 64 + m * 16 + l15) * 64 + l4 * 16));
    #pragma unroll
    for (int n = 0; n < 4; ++n) {
      bf16x8 bfr = *(const bf16x8*)(pb + ((wc * 64 + n * 16 + l15) * 64 + l4 * 16));
      #pragma unroll
      for (int m = 0; m < 4; ++m)
        acc[m][n] = __builtin_amdgcn_mfma_f32_16x16x32_bf16(af[m], bfr, acc[m][n], 0, 0, 0);
    }
    cur ^= 1;
  }

  // exact x2 (each X row staged by a fixed thread quad; cb==0 covers all rows once)
  if (cb == 0) {
    ss += __shfl_xor(ss, 1, 64);
    ss += __shfl_xor(ss, 2, 64);
    if ((tid & 3) == 0) x2g[rowbase + arow] = ss;
  }

  // ---- mining epilogue: score = t2[c] - 2*dot; extract lab score; per-row argmin ----
  float t2v[4];
  #pragma unroll
  for (int n = 0; n < 4; ++n) t2v[n] = t2g[colbase + wc * 64 + n * 16 + l15];

  #pragma unroll
  for (int m = 0; m < 4; ++m) {
    #pragma unroll
    for (int j = 0; j < 4; ++j) {
      const int rowl = wr * 64 + m * 16 + l4 * 4 + j;
      const int lab = sLab[rowl];
      float bv = 3.0e38f; int bi = 0x7fffffff;
      #pragma unroll
      for (int n = 0; n < 4; ++n) {
        const int col = colbase + wc * 64 + n * 16 + l15;
        const float sc = t2v[n] - 2.0f * acc[m][n][j];
        if (col == lab) slab[rowbase + rowl] = sc;       // d_ap^2 - x2 (pre-exclusion)
        const float sce = (col == lab) ? 3.2e38f : sc;
        if (sce < bv || (sce == bv && col < bi)) { bv = sce; bi = col; }
      }
      #pragma unroll
      for (int mk = 1; mk < 16; mk <<= 1) {              // reduce across l15 (cols)
        const float ov = __shfl_xor(bv, mk, 64);
        const int   oi = __shfl_xor(bi, mk, 64);
        if (ov < bv || (ov == bv && oi < bi)) { bv = ov; bi = oi; }
      }
      if (l15 == 0) sMin[rowl][wc] = make_float2(bv, __int_as_float(bi));
    }
  }
  __syncthreads();
  if (tid < BM) {
    float2 p = sMin[tid][0];
    #pragma unroll
    for (int q = 1; q < 4; ++q) {
      float2 o = sMin[tid][q];
      if (o.x < p.x || (o.x == p.x && __float_as_int(o.y) < __float_as_int(p.y))) p = o;
    }
    pairs[(size_t)(rowbase + tid) * NCB + cb] = p;
  }
}

// ---------- finalize: combine col-block partials, hinge, mean ----------
__global__ __launch_bounds__(256) void finalize_kernel(
    const float2* __restrict__ pairs, const float* __restrict__ slab,
    const float* __restrict__ x2g, float* __restrict__ out) {
  const int r = blockIdx.x * 256 + threadIdx.x;
  float2 p = pairs[(size_t)r * NCB];
  #pragma unroll
  for (int q = 1; q < NCB; ++q) {
    float2 o = pairs[(size_t)r * NCB + q];
    if (o.x < p.x || (o.x == p.x && __float_as_int(o.y) < __float_as_int(p.y))) p = o;
  }
  const float x2v = x2g[r];
  const float dap = sqrtf(fmaxf(x2v + slab[r], 0.0f));
  const float dan = sqrtf(fmaxf(x2v + p.x, 0.0f));
  float h = fmaxf(dap - dan + 1.0f, 0.0f);
  #pragma unroll
  for (int mk = 1; mk < 64; mk <<= 1) h += __shfl_xor(h, mk, 64);
  __shared__ float red[4];
  if ((threadIdx.x & 63) == 0) red[threadIdx.x >> 6] = h;
  __syncthreads();
  if (threadIdx.x == 0)
    atomicAdd(out, (red[0] + red[1] + red[2] + red[3]) * (1.0f / (float)NB));
}

extern "C" void kernel_launch(void* const* d_in, const int* in_sizes, int n_in,
                              void* d_out, int out_size, void* d_ws, size_t ws_size,
                              hipStream_t stream) {
  const float* X = (const float*)d_in[0];        // [16384,1024] f32
  const int* labels = (const int*)d_in[1];       // [16384] int
  const float* Tf = (const float*)d_in[2];       // [1000,1024] f32
  float* out = (float*)d_out;                    // scalar f32

  char* ws = (char*)d_ws;
  unsigned short* Tb = (unsigned short*)ws;                       // 2 MB
  float* t2   = (float*)(ws + 2097152);                           // 4 KB
  float* x2   = (float*)(ws + 2097152 + 4096);                    // 64 KB
  float* slab = (float*)(ws + 2097152 + 4096 + 65536);            // 64 KB
  float2* pairs = (float2*)(ws + 2097152 + 4096 + 131072);        // 512 KB

  hipMemsetAsync(d_out, 0, sizeof(float), stream);
  prep_kernel<<<NCP, 256, 0, stream>>>(Tf, Tb, t2);
  mine2_kernel<<<(NB / BM) * NCB, 512, 0, stream>>>(X, labels, Tb, t2, x2, slab, pairs);
  finalize_kernel<<<NB / 256, 256, 0, stream>>>(pairs, slab, x2, out);
}